// Round 7
// baseline (149.752 us; speedup 1.0000x reference)
//
#include <hip/hip_runtime.h>
#include <hip/hip_bf16.h>
#include <stdint.h>

// DiffLogic: 3-layer differentiable logic network.
// Round 7: R6 structure (500 blocks x 1024 threads, bf16 activations) +
// VOLATILE two-phase gather: all 16 loads (8 gates x A,B; 8B each) issued
// as volatile in program order before any use -> compiler cannot sink them,
// ~16 loads in flight per wave instead of 2. VGPR check: expect ~60-72.

#define BATCH   256
#define IN_DIM  1024
#define WIDTH   64000
#define NGROUP  10
#define GSIZE   6400      // WIDTH / NGROUP
#define TAU     30.0f
#define NWAVE   16        // waves per block
#define GPW     8         // serial gates per wave
#define GPB     (NWAVE*GPW)   // 128 gates/block; 6400 % 128 == 0
#define NBLK    (WIDTH/GPB)   // 500

typedef unsigned short ushort_t;

static __device__ __forceinline__ ushort_t f2bf(float f) {   // RNE
    uint32_t u = __float_as_uint(f);
    return (ushort_t)((u + 0x7fffu + ((u >> 16) & 1u)) >> 16);
}
static __device__ __forceinline__ float bfbits(uint32_t hi16) {
    return __uint_as_float(hi16 << 16);
}

// ---------------------------------------------------------------- transpose
// x:(256,1024) f32 row-major -> xT:(1024,256) bf16
__global__ __launch_bounds__(256) void transpose_kernel(
    const float* __restrict__ x, ushort_t* __restrict__ xT)
{
    __shared__ float tile[64][65];
    const int c0 = (blockIdx.x & 15) * 64;
    const int b0 = (blockIdx.x >> 4) * 64;
    const int lt = threadIdx.x & 63;
    const int wt = threadIdx.x >> 6;
    for (int r = wt; r < 64; r += 4)
        tile[r][lt] = x[(b0 + r) * IN_DIM + c0 + lt];
    __syncthreads();
    for (int r = wt; r < 64; r += 4)
        xT[(c0 + r) * BATCH + b0 + lt] = f2bf(tile[lt][r]);
}

// ---------------------------------------------------------------- coefficients
__global__ __launch_bounds__(256) void coef_kernel(
    const float* __restrict__ w1, const float* __restrict__ w2,
    const float* __restrict__ w3,
    float4* __restrict__ c1o, float4* __restrict__ c2o, float4* __restrict__ c3o)
{
    const int id = blockIdx.x * 256 + threadIdx.x;
    const int layer = id / WIDTH;
    const int j = id - layer * WIDTH;
    const float* w = (layer == 0) ? w1 : (layer == 1) ? w2 : w3;
    float4* cc     = (layer == 0) ? c1o : (layer == 1) ? c2o : c3o;

    const float4* w4 = (const float4*)(w + (size_t)j * 16);
    float4 q0 = w4[0], q1 = w4[1], q2 = w4[2], q3 = w4[3];
    float p[16] = {q0.x,q0.y,q0.z,q0.w, q1.x,q1.y,q1.z,q1.w,
                   q2.x,q2.y,q2.z,q2.w, q3.x,q3.y,q3.z,q3.w};
    float m = p[0];
    #pragma unroll
    for (int i = 1; i < 16; ++i) m = fmaxf(m, p[i]);
    float s = 0.f;
    #pragma unroll
    for (int i = 0; i < 16; ++i) { p[i] = __expf(p[i] - m); s += p[i]; }
    const float inv = 1.0f / s;

    float c0 = (p[8]+p[9]+p[10]+p[11]+p[12]+p[13]+p[14]+p[15]) * inv;
    float c1 = (p[2]+p[3]+p[6]+p[7] - p[8]-p[9]-p[12]-p[13]) * inv;
    float c2 = (p[4]+p[5]+p[6]+p[7] - p[8]-p[9]-p[10]-p[11]) * inv;
    float c3 = (p[1]-p[2]-p[4]-2.f*p[6]-p[7]+p[8]+2.f*p[9]+p[11]+p[13]-p[14]) * inv;
    cc[j] = make_float4(c0, c1, c2, c3);
}

// ---------------------------------------------------------------- logic layer
// in : (in_width, 256) bf16 columns (width-major, batch contiguous).
// Column = 512 B = 64 x uint64; lane's slice = 8 B (4 bf16).
template<bool FINAL>
__global__ __launch_bounds__(1024) void logic_layer_kernel(
    const ushort_t* __restrict__ in,
    const float4*   __restrict__ coefs,
    const int*      __restrict__ ia,
    const int*      __restrict__ ib,
    ushort_t*       __restrict__ out,
    float*          __restrict__ red_out)
{
    const int lane = threadIdx.x & 63;
    const int wave = __builtin_amdgcn_readfirstlane(threadIdx.x >> 6);
    const int jw = blockIdx.x * GPB + wave * GPW;   // wave's 8 contiguous gates

    int av[GPW], bv[GPW];
    #pragma unroll
    for (int u = 0; u < GPW; ++u) { av[u] = ia[jw + u]; bv[u] = ib[jw + u]; }

    // Phase 1: issue all 16 gathers as VOLATILE loads (program-order pinned;
    // compiler cannot sink them to uses -> all outstanding simultaneously).
    const uint64_t* base = (const uint64_t*)in;
    uint64_t Ar[GPW], Br[GPW];
    #pragma unroll
    for (int u = 0; u < GPW; ++u) {
        Ar[u] = *(volatile const uint64_t*)(base + (size_t)av[u] * 64 + lane);
        Br[u] = *(volatile const uint64_t*)(base + (size_t)bv[u] * 64 + lane);
    }

    // Phase 2: unpack + compute (+ store / accumulate).
    float4 acc = make_float4(0.f, 0.f, 0.f, 0.f);
    #pragma unroll
    for (int u = 0; u < GPW; ++u) {
        const float4 c = coefs[jw + u];
        const uint64_t a = Ar[u], b = Br[u];
        const float Ax = bfbits((uint32_t)a & 0xffffu);
        const float Ay = bfbits(((uint32_t)a >> 16) & 0xffffu);
        const float Az = bfbits((uint32_t)(a >> 32) & 0xffffu);
        const float Aw = bfbits((uint32_t)(a >> 48));
        const float Bx = bfbits((uint32_t)b & 0xffffu);
        const float By = bfbits(((uint32_t)b >> 16) & 0xffffu);
        const float Bz = bfbits((uint32_t)(b >> 32) & 0xffffu);
        const float Bw = bfbits((uint32_t)(b >> 48));
        float4 r;
        r.x = fmaf(c.w, Ax * Bx, fmaf(c.z, Bx, fmaf(c.y, Ax, c.x)));
        r.y = fmaf(c.w, Ay * By, fmaf(c.z, By, fmaf(c.y, Ay, c.x)));
        r.z = fmaf(c.w, Az * Bz, fmaf(c.z, Bz, fmaf(c.y, Az, c.x)));
        r.w = fmaf(c.w, Aw * Bw, fmaf(c.z, Bw, fmaf(c.y, Aw, c.x)));
        if (FINAL) {
            acc.x += r.x; acc.y += r.y; acc.z += r.z; acc.w += r.w;
        } else {
            ushort4 o;
            o.x = f2bf(r.x); o.y = f2bf(r.y); o.z = f2bf(r.z); o.w = f2bf(r.w);
            ((ushort4*)(out + (size_t)(jw + u) * BATCH))[lane] = o;
        }
    }

    if (FINAL) {
        __shared__ float4 s[NWAVE][64];     // 16 KB
        s[wave][lane] = acc;
        __syncthreads();
        if (wave == 0) {
            float4 t = s[0][lane];
            #pragma unroll
            for (int w = 1; w < NWAVE; ++w) {
                float4 q = s[w][lane];
                t.x += q.x; t.y += q.y; t.z += q.z; t.w += q.w;
            }
            const float sc = 1.0f / TAU;
            const int grp = (blockIdx.x * GPB) / GSIZE;   // block within one group
            const int b0 = lane * 4;
            atomicAdd(&red_out[(b0 + 0) * NGROUP + grp], t.x * sc);
            atomicAdd(&red_out[(b0 + 1) * NGROUP + grp], t.y * sc);
            atomicAdd(&red_out[(b0 + 2) * NGROUP + grp], t.z * sc);
            atomicAdd(&red_out[(b0 + 3) * NGROUP + grp], t.w * sc);
        }
    }
}

// ---------------------------------------------------------------- launch
extern "C" void kernel_launch(void* const* d_in, const int* in_sizes, int n_in,
                              void* d_out, int out_size, void* d_ws, size_t ws_size,
                              hipStream_t stream)
{
    const float* x   = (const float*)d_in[0];
    const float* w1  = (const float*)d_in[1];
    const float* w2  = (const float*)d_in[2];
    const float* w3  = (const float*)d_in[3];
    const int*   ia1 = (const int*)d_in[4];
    const int*   ib1 = (const int*)d_in[5];
    const int*   ia2 = (const int*)d_in[6];
    const int*   ib2 = (const int*)d_in[7];
    const int*   ia3 = (const int*)d_in[8];
    const int*   ib3 = (const int*)d_in[9];
    float* out = (float*)d_out;

    // workspace: xT | h1 | h2 | c1 | c2 | c3 (~69 MB, 16B-aligned segments)
    char* ws = (char*)d_ws;
    ushort_t* xT = (ushort_t*)ws;
    ushort_t* h1 = (ushort_t*)(ws + ((size_t)IN_DIM * BATCH * 2));
    ushort_t* h2 = h1 + (size_t)WIDTH * BATCH;
    float*    c1 = (float*)(h2 + (size_t)WIDTH * BATCH);
    float*    c2 = c1 + (size_t)WIDTH * 4;
    float*    c3 = c2 + (size_t)WIDTH * 4;

    hipMemsetAsync(d_out, 0, (size_t)out_size * sizeof(float), stream);

    transpose_kernel<<<64, 256, 0, stream>>>(x, xT);
    coef_kernel<<<(3 * WIDTH) / 256, 256, 0, stream>>>(w1, w2, w3,
                                                       (float4*)c1, (float4*)c2, (float4*)c3);

    logic_layer_kernel<false><<<NBLK, 1024, 0, stream>>>(
        xT, (const float4*)c1, ia1, ib1, h1, nullptr);
    logic_layer_kernel<false><<<NBLK, 1024, 0, stream>>>(
        h1, (const float4*)c2, ia2, ib2, h2, nullptr);
    logic_layer_kernel<true><<<NBLK, 1024, 0, stream>>>(
        h2, (const float4*)c3, ia3, ib3, nullptr, out);
}